// Round 1
// 696.630 us; speedup vs baseline: 1.1184x; 1.1184x over previous
//
#include <hip/hip_runtime.h>

// 2-layer LSTM, B=512, T=1024, H=64 (tf LSTMCell, gates i,j,f,o, forget bias 1.0)
// One block (576 thr = 9 waves) per batch element.
//   Waves 0-7 (compute): wave w owns gate columns [32w, 32w+32); gate g = w>>1.
//   SPLIT-K: lanes 0-31 hold W1 rows 0..32 (incl x-row + bias), lanes 32-63
//   rows 33..64. Halves combined with one __shfl_xor(p,32) -> ONE barrier/step.
//   This revision (vs 779us baseline): wave-specialized separate loops (no
//   per-step cw branches), t-loop unrolled x4 with STATIC parity addressing,
//   branch-free unified activation act = aa + bb*rcp(1+exp2(mm*p+kk)),
//   both halves write gs (same addr/value -> no exec mask), gs relayout
//   [2][64][4] so phase 2 is one ds_read_b128, xs read amortized (b128/4 steps),
//   and ALL layer-2 work (dot + recurrence) moved to wave 8 reading
//   parity-buffered h1s one step behind.
//   33 weights/thread keeps VGPR < 64 so weights stay register-resident
//   (rounds 4-6 lesson: 65/thread forced remat -> L1-BW bound).

#define TT 1024

__device__ __forceinline__ float fsig(float x) {
    return __builtin_amdgcn_rcpf(1.f + __expf(-x));
}
__device__ __forceinline__ float ftanh(float x) {
    return 1.f - 2.f * __builtin_amdgcn_rcpf(1.f + __expf(2.f * x));
}

template <int Ctrl, int Rmask>
__device__ __forceinline__ float dpp_add(float x) {
    int t = __builtin_amdgcn_update_dpp(0, __float_as_int(x), Ctrl, Rmask, 0xf, true);
    return x + __int_as_float(t);
}
// Sum across 64 lanes; result valid in lane 63. 6 dependent VALU ops.
__device__ __forceinline__ float wave_sum64(float x) {
    x = dpp_add<0x111, 0xf>(x); // row_shr:1
    x = dpp_add<0x112, 0xf>(x); // row_shr:2
    x = dpp_add<0x114, 0xf>(x); // row_shr:4
    x = dpp_add<0x118, 0xf>(x); // row_shr:8
    x = dpp_add<0x142, 0xa>(x); // row_bcast:15
    x = dpp_add<0x143, 0xc>(x); // row_bcast:31 ; lane63 = total
    return x;
}

__global__ __launch_bounds__(576, 6) void lstm2_kernel(
    const float* __restrict__ x,    // [B, T]
    const float* __restrict__ W1,   // [65, 256]; row0 = x, rows 1..64 = h1
    const float* __restrict__ b1,   // [256]
    const float* __restrict__ W2,   // [65, 4]; rows 0..63 = h1, row 64 = h2
    const float* __restrict__ b2,   // [4]
    float* __restrict__ y)          // [B, T]
{
    __shared__ __align__(16) float xs[TT];
    __shared__ __align__(16) float h1s[2][64];     // parity-buffered h1
    __shared__ __align__(16) float gs[2][64][4];   // parity-buffered gates, [unit][gate]

    const int tid  = threadIdx.x;
    const int b    = blockIdx.x;
    const int lane = tid & 63;
    const int cw   = tid >> 6;        // 0..7 compute waves, 8 = layer-2 wave
    const int half = lane >> 5;       // split-k half within the wave
    const int l31  = lane & 31;

    // stage x row into LDS (coalesced float4)
    if (tid < 256) {
        ((float4*)xs)[tid] = ((const float4*)(x + (size_t)b * TT))[tid];
    }
    if (tid < 128) ((float*)h1s)[tid] = 0.f;       // both parity buffers

    float* yrow = y + (size_t)b * TT;

    if (cw < 8) {
        // ---------------- compute waves ----------------
        const int col   = (cw << 5) | l31;         // gate column
        const int g     = cw >> 1;                 // gate id (wave-uniform)
        const int gunit = ((cw & 1) << 5) | l31;   // hidden unit this column feeds

        // per-thread layer-1 weights: 33 floats (half a column) in registers
        float w[33];
        float bias = 0.f;
        if (half == 0) {
            w[0] = W1[col];
            bias = b1[col];
#pragma unroll
            for (int j = 1; j <= 32; ++j) w[j] = W1[j * 256 + col];         // rows 1..32
        } else {
            w[0] = 0.f;                            // no x term, no bias in upper half
#pragma unroll
            for (int j = 1; j <= 32; ++j) w[j] = W1[(32 + j) * 256 + col];  // rows 33..64
        }

        // unified activation constants (wave-uniform, branch-free in loop):
        //   act = aa + bb * rcp(1 + exp2(mm*p + kk))
        //   i,o: sigmoid(p); f: sigmoid(p+1); j: tanh(p) = 1 - 2/(1+e^{2p})
        const float L2E = 1.4426950408889634f;
        const float mm = (g == 1) ? 2.f * L2E : -L2E;
        const float kk = (g == 2) ? -L2E : 0.f;
        const float aa = (g == 1) ? 1.f : 0.f;
        const float bb = (g == 1) ? -2.f : 1.f;

        const int hrow = half << 3;   // float4 base index into a 64-float h1 row
        float c1 = 0.f;               // replicated cell state of hidden unit `lane`
        __syncthreads();              // barrier #1 (xs/h1s staged)

        // One step; PAR is a compile-time 0/1 so all LDS addressing is
        // base-reg + immediate. Both halves hold identical p after the shfl,
        // so both write the same act to the same gs address (no exec mask).
#define STEP(PAR, XT) { \
        float a0 = fmaf((XT), w[0], bias), a1 = 0.f, a2 = 0.f, a3 = 0.f; \
        const float4* hb = (const float4*)(&h1s[(PAR) ^ 1][0]); \
        _Pragma("unroll") \
        for (int q = 0; q < 8; ++q) { \
            float4 h4 = hb[hrow + q]; \
            a0 = fmaf(h4.x, w[1 + 4 * q], a0); \
            a1 = fmaf(h4.y, w[2 + 4 * q], a1); \
            a2 = fmaf(h4.z, w[3 + 4 * q], a2); \
            a3 = fmaf(h4.w, w[4 + 4 * q], a3); \
        } \
        float p = (a0 + a1) + (a2 + a3); \
        p += __shfl_xor(p, 32); \
        float act = fmaf(bb, __builtin_amdgcn_rcpf(1.f + exp2f(fmaf(mm, p, kk))), aa); \
        gs[PAR][gunit][g] = act; \
        __syncthreads(); \
        float4 g4 = *(const float4*)(&gs[PAR][lane][0]); \
        c1 = fmaf(c1, g4.z, g4.x * g4.y); \
        float rr = __builtin_amdgcn_rcpf(1.f + exp2f(c1 * (2.f * L2E))); \
        float tt_ = rr * g4.w; \
        h1s[PAR][lane] = fmaf(-2.f, tt_, g4.w); }

        for (int t = 0; t < TT; t += 4) {
            float4 x4 = *(const float4*)(xs + t);
            STEP(0, x4.x)
            STEP(1, x4.y)
            STEP(0, x4.z)
            STEP(1, x4.w)
        }
#undef STEP
        __syncthreads();              // tail barrier (lets wave 8 see h1(TT-1))
    } else {
        // ---------------- wave 8: full layer 2, one step behind ----------------
        float4 w2g4 = *(const float4*)(W2 + lane * 4);   // W2[lane][0..3]
        const float w2h0 = W2[256], w2h1 = W2[257], w2h2 = W2[258], w2h3 = W2[259];
        const float b20 = b2[0], b21 = b2[1], b22 = b2[2], b23 = b2[3];
        float c2 = 0.f, h2 = 0.f;     // state lives in lane 63
        __syncthreads();              // barrier #1

        for (int t = 0; t < TT; ++t) {
            __syncthreads();          // rendezvous with compute waves' mid-step barrier
            if (t > 0) {
                const float hv = h1s[(t - 1) & 1][lane];   // h1(t-1)
                const float d0 = wave_sum64(hv * w2g4.x);
                const float d1 = wave_sum64(hv * w2g4.y);
                const float d2 = wave_sum64(hv * w2g4.z);
                const float d3 = wave_sum64(hv * w2g4.w);
                if (lane == 63) {
                    const float i2 = fsig (fmaf(h2, w2h0, d0) + b20);
                    const float j2 = ftanh(fmaf(h2, w2h1, d1) + b21);
                    const float f2 = fsig (fmaf(h2, w2h2, d2) + b22 + 1.f);
                    const float o2 = fsig (fmaf(h2, w2h3, d3) + b23);
                    c2 = fmaf(c2, f2, i2 * j2);
                    h2 = ftanh(c2) * o2;
                    yrow[t - 1] = h2;
                }
            }
        }
        __syncthreads();              // matches compute waves' tail barrier
        {   // final step (t = TT-1)
            const float hv = h1s[(TT - 1) & 1][lane];
            const float d0 = wave_sum64(hv * w2g4.x);
            const float d1 = wave_sum64(hv * w2g4.y);
            const float d2 = wave_sum64(hv * w2g4.z);
            const float d3 = wave_sum64(hv * w2g4.w);
            if (lane == 63) {
                const float i2 = fsig (fmaf(h2, w2h0, d0) + b20);
                const float j2 = ftanh(fmaf(h2, w2h1, d1) + b21);
                const float f2 = fsig (fmaf(h2, w2h2, d2) + b22 + 1.f);
                const float o2 = fsig (fmaf(h2, w2h3, d3) + b23);
                c2 = fmaf(c2, f2, i2 * j2);
                h2 = ftanh(c2) * o2;
                yrow[TT - 1] = h2;
            }
        }
    }
}

extern "C" void kernel_launch(void* const* d_in, const int* in_sizes, int n_in,
                              void* d_out, int out_size, void* d_ws, size_t ws_size,
                              hipStream_t stream) {
    const float* x  = (const float*)d_in[0];
    const float* W1 = (const float*)d_in[1];
    const float* b1 = (const float*)d_in[2];
    const float* W2 = (const float*)d_in[3];
    const float* b2 = (const float*)d_in[4];
    float* y = (float*)d_out;
    lstm2_kernel<<<512, 576, 0, stream>>>(x, W1, b1, W2, b2, y);
}